// Round 15
// baseline (512.951 us; speedup 1.0000x reference)
//
#include <hip/hip_runtime.h>
#include <cstdio>

#define N_TOK 16384
#define CDIM  512

typedef unsigned short ushort_t;
typedef _Float16 f16;
typedef __attribute__((ext_vector_type(8))) _Float16 f16x8;
typedef __attribute__((ext_vector_type(4))) _Float16 f16x4;
typedef __attribute__((ext_vector_type(4))) float f32x4;

// ---------------------------------------------------------------- helpers
__device__ __forceinline__ float fast_pow(float x, float p) {
  return __builtin_amdgcn_exp2f(p * __builtin_amdgcn_logf(x));
}
__device__ __forceinline__ void gl_lds16(const void* g, void* l) {
  __builtin_amdgcn_global_load_lds((const __attribute__((address_space(1))) void*)g,
                                   (__attribute__((address_space(3))) void*)l, 16, 0, 0);
}
// permuted fp16 column index (must match cvt_perm_kernel): row r, col k
__device__ __forceinline__ int perm_col(int k, int r) {
  const int kg = k >> 5, c8 = (k >> 3) & 3, e = k & 7;
  return kg * 32 + ((c8 ^ ((r >> 1) & 3)) * 8) + e;
}

// ---------------------------------------------------------------- zero
__global__ void zero_kernel(float* __restrict__ p, int n) {
  int i = blockIdx.x * blockDim.x + threadIdx.x;
  if (i < n) p[i] = 0.f;
}

// ---------------------------------------------------------------- 1/softplus(scale), 512 values
__global__ void sp_kernel(const float* __restrict__ scale, float* __restrict__ inv_s) {
  int i = blockIdx.x * blockDim.x + threadIdx.x;
  if (i < 512) {
    float sc = scale[i];
    float s = (sc > 20.f) ? sc : log1pf(expf(sc));
    inv_s[i] = 1.0f / s;
  }
}

// ---------------------------------------------------------------- fp32 -> fp16, chunk-permuted (512-col rows)
__global__ __launch_bounds__(256) void cvt_perm_kernel(const float* __restrict__ in,
                                                       f16* __restrict__ out, int n4) {
  int i = blockIdx.x * blockDim.x + threadIdx.x;
  const int stride = gridDim.x * blockDim.x;
  for (; i < n4; i += stride) {
    float4 v = ((const float4*)in)[i];
    const int r = i >> 7;
    const int f = i & 127;
    const int kg = f >> 3;
    const int c = (f >> 1) & 3;
    const int e = (f & 1) * 4;
    const int dst = r * 512 + kg * 32 + ((c ^ ((r >> 1) & 3)) * 8) + e;
    f16x4 h;
    h.x = (f16)v.x; h.y = (f16)v.y; h.z = (f16)v.z; h.w = (f16)v.w;
    *(f16x4*)&out[dst] = h;
  }
}

// ---------------------------------------------------------------- fp16 MFMA GEMM, full-DMA
template <int OUT16>
__global__ __launch_bounds__(256, 4) void gemm_f16(const f16* __restrict__ A,
                                                   const f16* __restrict__ Bw,
                                                   const float* __restrict__ b1,
                                                   const float* __restrict__ b2,
                                                   float* __restrict__ C32,
                                                   f16* __restrict__ C16,
                                                   const int K, const int nY,
                                                   const int ncol1, const int ldc) {
  __shared__ __align__(16) f16 SMEM[16896];
  const int t = threadIdx.x;
  const int lane = t & 63;
  const int w = t >> 6;
  const int wr = w >> 1, wc = w & 1;

  const int id = blockIdx.x;
  const int xcd = id & 7;
  const int j = id >> 3;
  const int xpc = (int)(gridDim.x) / (nY * 8);
  const int xloc = j / nY;
  const int y = j - xloc * nY;
  const size_t bm = (size_t)(xcd * xpc + xloc) * 128;
  const int bn = y * 128;

  const int lr = lane & 15;
  const int ksl = lane >> 4;

  f32x4 acc[4][4] = {};

  auto stage = [&](int k0, int buf) {
    const int rsub = lane >> 2;
    const int csub = (lane & 3) * 8;
    const size_t ga = (bm + w * 32 + rsub) * (size_t)K + k0 + csub;
    const size_t gb = ((size_t)(bn + w * 32 + rsub)) * K + k0 + csub;
    f16* Ab = SMEM + buf * 4096;
    f16* Bb = SMEM + 8192 + buf * 4096;
    gl_lds16(A + ga,                   Ab + (w * 32) * 32);
    gl_lds16(A + ga + 16 * (size_t)K,  Ab + (w * 32 + 16) * 32);
    gl_lds16(Bw + gb,                  Bb + (w * 32) * 32);
    gl_lds16(Bw + gb + 16 * (size_t)K, Bb + (w * 32 + 16) * 32);
  };

  const int nsteps = K >> 5;
  stage(0, 0);
  for (int s = 0; s < nsteps; ++s) {
    const int buf = s & 1;
    __syncthreads();
    const f16* Ab = SMEM + buf * 4096;
    const f16* Bb = SMEM + 8192 + buf * 4096;
    f16x8 a[4], b[4];
#pragma unroll
    for (int i = 0; i < 4; ++i) {
      const int rA = wr * 64 + i * 16 + lr;
      a[i] = *(const f16x8*)&Ab[rA * 32 + ((ksl ^ ((rA >> 1) & 3)) * 8)];
      const int rB = wc * 64 + i * 16 + lr;
      b[i] = *(const f16x8*)&Bb[rB * 32 + ((ksl ^ ((rB >> 1) & 3)) * 8)];
    }
    if (s + 1 < nsteps) stage((s + 1) << 5, buf ^ 1);
#pragma unroll
    for (int mi = 0; mi < 4; ++mi)
#pragma unroll
      for (int ni = 0; ni < 4; ++ni)
        acc[mi][ni] = __builtin_amdgcn_mfma_f32_16x16x32_f16(a[mi], b[ni], acc[mi][ni], 0, 0, 0);
  }

  const int rg = (lane >> 4) << 2;
  if (OUT16) {
    __syncthreads();
#pragma unroll
    for (int ni = 0; ni < 4; ++ni) {
      const int cl = wc * 64 + ni * 16 + lr;
      const int cg = bn + cl;
      const float bs = (cg < ncol1) ? b1[cg] : b2[cg - ncol1];
#pragma unroll
      for (int mi = 0; mi < 4; ++mi)
#pragma unroll
        for (int j2 = 0; j2 < 4; ++j2)
          SMEM[(wr * 64 + mi * 16 + rg + j2) * 132 + cl] = (f16)(acc[mi][ni][j2] + bs);
    }
    __syncthreads();
#pragma unroll
    for (int i = 0; i < 8; ++i) {
      const int idx = i * 256 + t;
      const int rl = idx >> 4, ch = (idx & 15) * 8;
      *(f16x8*)&C16[(bm + rl) * (size_t)ldc + bn + ch] = *(const f16x8*)&SMEM[rl * 132 + ch];
    }
  } else {
#pragma unroll
    for (int ni = 0; ni < 4; ++ni) {
      const int col = bn + wc * 64 + ni * 16 + lr;
      const float bs = (col < ncol1) ? b1[col] : b2[col - ncol1];
#pragma unroll
      for (int mi = 0; mi < 4; ++mi) {
        float* Cp = C32 + (bm + wr * 64 + mi * 16 + rg) * (size_t)ldc + col;
#pragma unroll
        for (int j2 = 0; j2 < 4; ++j2)
          Cp[(size_t)j2 * ldc] = acc[mi][ni][j2] + bs;
      }
    }
  }
}

// ---------------------------------------------------------------- row norms only: rowscale[row] = {qn/pqn, kn/pkn}
// wave-per-row, shfl-only; q,k stay RAW in qkv16 (consumers apply the map).
__global__ __launch_bounds__(256) void norm_kernel(const f16* __restrict__ qkv,
                                                   const float* __restrict__ inv_s,
                                                   const float* __restrict__ ff,
                                                   float* __restrict__ rowscale) {
  const int t = threadIdx.x, lane = t & 63, w = t >> 6;
  const int row = blockIdx.x * 4 + w;
  const f16* qr = qkv + (size_t)row * 1536 + lane * 8;
  const f16* kr = qr + 512;
  f16x8 qh = *(const f16x8*)qr;
  f16x8 kh = *(const f16x8*)kr;
  float is[8], fv[8];
  *(float4*)&is[0] = *(const float4*)(inv_s + lane * 8);
  *(float4*)&is[4] = *(const float4*)(inv_s + lane * 8 + 4);
  *(float4*)&fv[0] = *(const float4*)(ff + lane * 8);
  *(float4*)&fv[4] = *(const float4*)(ff + lane * 8 + 4);

  float sq = 0.f, sk = 0.f, sq2 = 0.f, sk2 = 0.f;
#pragma unroll
  for (int i = 0; i < 8; ++i) {
    const float qv = fmaf(fmaxf((float)qh[i], 0.f), is[i], 1e-6f * is[i]);
    const float kv = fmaf(fmaxf((float)kh[i], 0.f), is[i], 1e-6f * is[i]);
    sq += qv * qv;
    sk += kv * kv;
    const float pq = fast_pow(qv, fv[i]);
    const float pk = fast_pow(kv, fv[i]);
    sq2 += pq * pq;
    sk2 += pk * pk;
  }
#pragma unroll
  for (int off = 1; off < 64; off <<= 1) {
    sq += __shfl_xor(sq, off);
    sk += __shfl_xor(sk, off);
    sq2 += __shfl_xor(sq2, off);
    sk2 += __shfl_xor(sk2, off);
  }
  if (lane == 0) {
    rowscale[(size_t)row * 2]     = sqrtf(sq) / sqrtf(sq2);
    rowscale[(size_t)row * 2 + 1] = sqrtf(sk) / sqrtf(sk2);
  }
}

// ---------------------------------------------------------------- kv_mat[bh] = k^T v / N (+ fused ksum)
// k-nonlin applied on the fly from raw k: kc = pow((relu(k)+eps)*is, f) * kscale[row]
__global__ __launch_bounds__(256, 4) void kvmat16_kernel(const f16* __restrict__ qkv,
                                                         const float* __restrict__ inv_s,
                                                         const float* __restrict__ ff,
                                                         const float* __restrict__ rowscale,
                                                         float* __restrict__ kvm,
                                                         float* __restrict__ ksum) {
  __shared__ float tile[64 * 66];
  const int bh = blockIdx.y;
  const int b = bh >> 3, h = bh & 7;
  const int chunk = blockIdx.x;
  const int t = threadIdx.x, lane = t & 63, w = t >> 6;
  const int r0 = lane >> 3;
  const int c0 = lane & 7;
  const int cg = h * 64 + lane;
  const float is = inv_s[cg], fe = ff[cg], epsis = 1e-6f * is;
  float acc[8][8] = {};
  float kacc = 0.f;
  const int row0 = b * N_TOK + chunk * 512 + w * 128;
  const size_t base = (size_t)row0 * 1536 + 512 + h * 64;
  const f16* kp = qkv + base + lane;
  const f16* vp = qkv + base + 512 + lane;

  float kcur = (float)kp[0], vcur = (float)vp[0];
  float kscur = rowscale[(size_t)row0 * 2 + 1];
  auto body = [&](float kraw, float vc, float ksc) {
    const float kc = fast_pow(fmaf(fmaxf(kraw, 0.f), is, epsis), fe) * ksc;
    kacc += kc;
    float kk[8], vv[8];
#pragma unroll
    for (int i = 0; i < 8; ++i) {
      kk[i] = __shfl(kc, r0 + i * 8);
      vv[i] = __shfl(vc, c0 + i * 8);
    }
#pragma unroll
    for (int i = 0; i < 8; ++i)
#pragma unroll
      for (int j = 0; j < 8; ++j)
        acc[i][j] = fmaf(kk[i], vv[j], acc[i][j]);
  };
  for (int r = 0; r < 127; ++r) {
    const float knx = (float)kp[(size_t)(r + 1) * 1536];
    const float vnx = (float)vp[(size_t)(r + 1) * 1536];
    const float ksnx = rowscale[(size_t)(row0 + r + 1) * 2 + 1];
    body(kcur, vcur, kscur);
    kcur = knx; vcur = vnx; kscur = ksnx;
  }
  body(kcur, vcur, kscur);

  atomicAdd(&ksum[b * 512 + h * 64 + lane], kacc);

  for (int ww = 0; ww < 4; ++ww) {
    if (w == ww) {
#pragma unroll
      for (int i = 0; i < 8; ++i)
#pragma unroll
        for (int j = 0; j < 8; ++j) {
          const int a = (r0 + i * 8) * 66 + c0 + j * 8;
          tile[a] = (ww == 0) ? acc[i][j] : tile[a] + acc[i][j];
        }
    }
    __syncthreads();
  }
  const float scl = 1.0f / (float)N_TOK;
#pragma unroll
  for (int i = 0; i < 16; ++i) {
    const int idx = i * 256 + t;
    const int rr = idx >> 6, cc = idx & 63;
    atomicAdd(&kvm[(size_t)bh * 4096 + idx], tile[rr * 66 + cc] * scl);
  }
}

// ---------------------------------------------------------------- kvm fp32 -> transposed, chunk-swizzled fp16
__global__ void cvt_kvmT_kernel(const float* __restrict__ kvm, f16* __restrict__ kvmT16) {
  const int bh = blockIdx.x, t = threadIdx.x;
#pragma unroll
  for (int i = 0; i < 16; ++i) {
    const int e = i * 256 + t;            // 0..4095 = din*64 + d
    const int din = e >> 6, d = e & 63;
    const float v = kvm[(size_t)bh * 4096 + e];
    const int c = din >> 3, ce = din & 7;
    kvmT16[(size_t)bh * 4096 + d * 64 + ((c ^ (d & 7)) * 8) + ce] = (f16)v;
  }
}

// ---------------------------------------------------------------- MFMA attention: y = (q_nl @ kvm) * z, perm fp16 out
// q-nonlin applied during reg-staged LDS fill (raw q in, final q into QS).
__global__ __launch_bounds__(256, 4) void attn_mfma_kernel(const f16* __restrict__ qkv,
                                                           const f16* __restrict__ kvmT16,
                                                           const float* __restrict__ ksum,
                                                           const float* __restrict__ inv_s,
                                                           const float* __restrict__ ff,
                                                           const float* __restrict__ rowscale,
                                                           f16* __restrict__ y16) {
  __shared__ __align__(16) f16 QS[128 * 64];   // [row][chunk ^ (row&7)]
  __shared__ __align__(16) f16 KM[64 * 64];    // [d][chunk ^ (d&7)] (pre-swizzled)
  __shared__ float kms[64];
  __shared__ float zl[128];
  const int bh = blockIdx.y;
  const int b = bh >> 3, h = bh & 7;
  const int tok0 = blockIdx.x * 128;
  const int t = threadIdx.x, lane = t & 63, w = t >> 6;

  // Q: 1024 chunks; apply nonlin per element, swizzled LDS store
#pragma unroll
  for (int i = 0; i < 4; ++i) {
    const int idx = i * 256 + t;
    const int row = idx >> 3, ch = idx & 7;
    const int gr = b * N_TOK + tok0 + row;
    const f16x8 v = *(const f16x8*)&qkv[(size_t)gr * 1536 + h * 64 + ch * 8];
    const float qsc = rowscale[(size_t)gr * 2];
    const int ci = h * 64 + ch * 8;
    float isv[8], fvv[8];
    *(float4*)&isv[0] = *(const float4*)&inv_s[ci];
    *(float4*)&isv[4] = *(const float4*)&inv_s[ci + 4];
    *(float4*)&fvv[0] = *(const float4*)&ff[ci];
    *(float4*)&fvv[4] = *(const float4*)&ff[ci + 4];
    f16x8 o;
#pragma unroll
    for (int e = 0; e < 8; ++e) {
      const float q_ = fmaf(fmaxf((float)v[e], 0.f), isv[e], 1e-6f * isv[e]);
      o[e] = (f16)(fast_pow(q_, fvv[e]) * qsc);
    }
    *(f16x8*)&QS[row * 64 + ((ch ^ (row & 7)) * 8)] = o;
  }
  // KM: verbatim vectorized copy
#pragma unroll
  for (int i = 0; i < 2; ++i) {
    const int idx = i * 256 + t;
    *(f16x8*)&KM[idx * 8] = *(const f16x8*)&kvmT16[(size_t)bh * 4096 + idx * 8];
  }
  if (t < 64) kms[t] = ksum[b * 512 + h * 64 + t];
  __syncthreads();

  // z per token: 2 threads/token, 32 din each
  {
    const int tok = t >> 1;
    const int ch0 = (t & 1) * 4;
    float p = 0.f;
#pragma unroll
    for (int c = 0; c < 4; ++c) {
      const int ch = ch0 + c;
      const f16x8 hv = *(const f16x8*)&QS[tok * 64 + ((ch ^ (tok & 7)) * 8)];
#pragma unroll
      for (int e = 0; e < 8; ++e) p += (float)hv[e] * kms[ch * 8 + e];
    }
    p += __shfl_xor(p, 1);
    if ((t & 1) == 0) zl[tok] = 1.0f / (p * (1.0f / (float)N_TOK) + 1e-6f);
  }
  __syncthreads();

  // fragments + MFMA
  const int lr = lane & 15, ksl = lane >> 4;
  f32x4 acc[2][4] = {};
  __builtin_amdgcn_s_setprio(1);
#pragma unroll
  for (int s = 0; s < 2; ++s) {
    f16x8 a[2], bfr[4];
#pragma unroll
    for (int mi = 0; mi < 2; ++mi) {
      const int row = w * 32 + mi * 16 + lr;
      a[mi] = *(const f16x8*)&QS[row * 64 + (((s * 4 + ksl) ^ (row & 7)) * 8)];
    }
#pragma unroll
    for (int ni = 0; ni < 4; ++ni) {
      const int dr = ni * 16 + lr;
      bfr[ni] = *(const f16x8*)&KM[dr * 64 + (((s * 4 + ksl) ^ (dr & 7)) * 8)];
    }
#pragma unroll
    for (int mi = 0; mi < 2; ++mi)
#pragma unroll
      for (int ni = 0; ni < 4; ++ni)
        acc[mi][ni] = __builtin_amdgcn_mfma_f32_16x16x32_f16(a[mi], bfr[ni], acc[mi][ni], 0, 0, 0);
  }
  __builtin_amdgcn_s_setprio(0);

  // epilogue: row = tokens, col = d (C/D layout col=lane&15, row=(lane>>4)*4+reg)
  const int rg = (lane >> 4) << 2;
#pragma unroll
  for (int mi = 0; mi < 2; ++mi)
#pragma unroll
    for (int ni = 0; ni < 4; ++ni)
#pragma unroll
      for (int j2 = 0; j2 < 4; ++j2) {
        const int row = w * 32 + mi * 16 + rg + j2;
        const int dcol = ni * 16 + lr;
        const float val = acc[mi][ni][j2] * zl[row];
        const int r = (int)(b * N_TOK) + tok0 + row;
        y16[(size_t)r * 512 + perm_col(h * 64 + dcol, r)] = (f16)val;
      }
}

// ---------------------------------------------------------------- depthwise 5x5 conv on v (raw fp16), RMW perm y16
__global__ __launch_bounds__(256, 4) void conv_kernel(const f16* __restrict__ qkv,
                                                      f16* __restrict__ y16,
                                                      const float* __restrict__ wconv,
                                                      const float* __restrict__ bconv) {
  __shared__ float vt[20 * 20 * 16];
  const int zidx = blockIdx.z;
  const int bh = zidx >> 2, cq = zidx & 3;
  const int b = bh >> 3, h = bh & 7;
  const int c0 = cq * 16;
  const int tx0 = blockIdx.x * 16, ty0 = blockIdx.y * 16;
  const int t = threadIdx.x;
  const size_t vcol = 1024 + h * 64 + c0;
#pragma unroll
  for (int i = 0; i < 7; ++i) {
    const int idx = i * 256 + t;
    if (idx < 1600) {
      const int pix = idx >> 2, c4 = (idx & 3) * 4;
      const int lx = pix % 20, ly = pix / 20;
      const int gx = tx0 + lx - 2, gy = ty0 + ly - 2;
      float4 val = make_float4(0.f, 0.f, 0.f, 0.f);
      if ((unsigned)gx < 128u && (unsigned)gy < 128u) {
        f16x4 hv = *(const f16x4*)&qkv[((size_t)(b * N_TOK) + gy * 128 + gx) * 1536 + vcol + c4];
        val = make_float4((float)hv.x, (float)hv.y, (float)hv.z, (float)hv.w);
      }
      *(float4*)&vt[pix * 16 + c4] = val;
    }
  }
  const int c = t & 15;
  const int dd = c0 + c;
  float w[25];
#pragma unroll
  for (int k = 0; k < 25; ++k) w[k] = wconv[dd * 25 + k];
  const float bb = bconv[dd];
  __syncthreads();
  const int slot = t >> 4;
  const int col = h * 64 + dd;
  for (int i = 0; i < 16; ++i) {
    const int pix = i * 16 + slot;
    const int px = pix & 15, py = pix >> 4;
    float acc = bb;
#pragma unroll
    for (int ky = 0; ky < 5; ++ky)
#pragma unroll
      for (int kx = 0; kx < 5; ++kx)
        acc = fmaf(w[ky * 5 + kx], vt[((py + ky) * 20 + (px + kx)) * 16 + c], acc);
    const int r = (int)(b * N_TOK) + (ty0 + py) * 128 + (tx0 + px);
    f16* p = &y16[(size_t)r * 512 + perm_col(col, r)];
    *p = (f16)((float)*p + acc);
  }
}

// ---------------------------------------------------------------- launch
extern "C" void kernel_launch(void* const* d_in, const int* in_sizes, int n_in,
                              void* d_out, int out_size, void* d_ws, size_t ws_size,
                              hipStream_t stream) {
  (void)n_in; (void)out_size;
  const float* x     = (const float*)d_in[0];
  const float* Wq    = (const float*)d_in[1];
  const float* bq    = (const float*)d_in[2];
  const float* Wkv   = (const float*)d_in[3];
  const float* bkv   = (const float*)d_in[4];
  const float* Wp    = (const float*)d_in[5];
  const float* bp    = (const float*)d_in[6];
  const float* ff    = (const float*)d_in[7];
  const float* scale = (const float*)d_in[8];
  const float* dwc_w = (const float*)d_in[9];
  const float* dwc_b = (const float*)d_in[10];

  const int B = in_sizes[0] / (N_TOK * CDIM);   // 4
  const int M = B * N_TOK;                      // 65536

  // ws layout: qkv16 [M][1536] fp16 | y16 [M][512] fp16 perm | ksum | kvm | scratch
  f16*   qkv16 = (f16*)d_ws;
  f16*   y16   = qkv16 + (size_t)M * 1536;
  float* ksum  = (float*)(y16 + (size_t)M * 512);
  float* kvm   = ksum + (size_t)B * 512;
  float* zscr  = kvm + (size_t)B * 8 * 4096;

  size_t need = ((size_t)M * 1536 + (size_t)B * 512 + (size_t)B * 8 * 4096 +
                 (size_t)B * 8 * N_TOK) * sizeof(float);   // known-good bound
  if (ws_size < need) {
    fprintf(stderr, "kernel_launch: ws too small (%zu < %zu)\n", ws_size, need);
    return;
  }

  // d_out head carve (dead until final GEMM): x16 (64 MB) + wqkv16 (1.5 MB)
  f16* x16    = (f16*)d_out;
  f16* wqkv16 = x16 + (size_t)M * 512;
  // z-scratch carve (2 MB): wp16 (512 KB) + inv_s (2 KB) + kvmT16 (256 KB) + rowscale (512 KB)
  f16* wp16      = (f16*)zscr;
  float* inv_s   = zscr + 131072;
  f16* kvmT16    = (f16*)(inv_s + 512);
  float* rowscale = (float*)(kvmT16 + 131072);

  const int nsmall = B * 512 + B * 8 * 4096;
  zero_kernel<<<(nsmall + 255) / 256, 256, 0, stream>>>(ksum, nsmall);
  sp_kernel<<<2, 256, 0, stream>>>(scale, inv_s);
  cvt_perm_kernel<<<4096, 256, 0, stream>>>(x, x16, M * 512 / 4);
  cvt_perm_kernel<<<256, 256, 0, stream>>>(Wq, wqkv16, 512 * 512 / 4);
  cvt_perm_kernel<<<512, 256, 0, stream>>>(Wkv, wqkv16 + 512 * 512, 1024 * 512 / 4);
  cvt_perm_kernel<<<256, 256, 0, stream>>>(Wp, wp16, 512 * 512 / 4);

  // fused q+kv projection -> fp16 qkv16 [M][1536] (raw, pre-nonlin)
  gemm_f16<1><<<(M / 128) * 12, 256, 0, stream>>>(x16, wqkv16, bq, bkv,
                                                  nullptr, qkv16, CDIM, 12, 512, 1536);

  norm_kernel<<<M / 4, 256, 0, stream>>>(qkv16, inv_s, ff, rowscale);
  kvmat16_kernel<<<dim3(32, B * 8), 256, 0, stream>>>(qkv16, inv_s, ff, rowscale, kvm, ksum);
  cvt_kvmT_kernel<<<B * 8, 256, 0, stream>>>(kvm, kvmT16);
  attn_mfma_kernel<<<dim3(N_TOK / 128, B * 8), 256, 0, stream>>>(qkv16, kvmT16, ksum,
                                                                 inv_s, ff, rowscale, y16);
  conv_kernel<<<dim3(8, 8, B * 8 * 4), 256, 0, stream>>>(qkv16, y16, dwc_w, dwc_b);

  // output projection: fp32 into d_out (overwrites dead x16/wqkv16)
  gemm_f16<0><<<(M / 128) * 4, 256, 0, stream>>>(y16, wp16, bp, bp,
                                                 (float*)d_out, nullptr, CDIM, 4, 512, 512);
}

// Round 16
// 438.444 us; speedup vs baseline: 1.1699x; 1.1699x over previous
//
#include <hip/hip_runtime.h>
#include <cstdio>

#define N_TOK 16384
#define CDIM  512

typedef unsigned short ushort_t;
typedef _Float16 f16;
typedef __attribute__((ext_vector_type(8))) _Float16 f16x8;
typedef __attribute__((ext_vector_type(4))) _Float16 f16x4;
typedef __attribute__((ext_vector_type(4))) float f32x4;

// ---------------------------------------------------------------- helpers
__device__ __forceinline__ float fast_pow(float x, float p) {
  return __builtin_amdgcn_exp2f(p * __builtin_amdgcn_logf(x));
}
__device__ __forceinline__ void gl_lds16(const void* g, void* l) {
  __builtin_amdgcn_global_load_lds((const __attribute__((address_space(1))) void*)g,
                                   (__attribute__((address_space(3))) void*)l, 16, 0, 0);
}
// permuted fp16 column index (must match cvt_perm_kernel): row r, col k
__device__ __forceinline__ int perm_col(int k, int r) {
  const int kg = k >> 5, c8 = (k >> 3) & 3, e = k & 7;
  return kg * 32 + ((c8 ^ ((r >> 1) & 3)) * 8) + e;
}

// ---------------------------------------------------------------- zero
__global__ void zero_kernel(float* __restrict__ p, int n) {
  int i = blockIdx.x * blockDim.x + threadIdx.x;
  if (i < n) p[i] = 0.f;
}

// ---------------------------------------------------------------- 1/softplus(scale), 512 values
__global__ void sp_kernel(const float* __restrict__ scale, float* __restrict__ inv_s) {
  int i = blockIdx.x * blockDim.x + threadIdx.x;
  if (i < 512) {
    float sc = scale[i];
    float s = (sc > 20.f) ? sc : log1pf(expf(sc));
    inv_s[i] = 1.0f / s;
  }
}

// ---------------------------------------------------------------- fp32 -> fp16, chunk-permuted (512-col rows)
__global__ __launch_bounds__(256) void cvt_perm_kernel(const float* __restrict__ in,
                                                       f16* __restrict__ out, int n4) {
  int i = blockIdx.x * blockDim.x + threadIdx.x;
  const int stride = gridDim.x * blockDim.x;
  for (; i < n4; i += stride) {
    float4 v = ((const float4*)in)[i];
    const int r = i >> 7;
    const int f = i & 127;
    const int kg = f >> 3;
    const int c = (f >> 1) & 3;
    const int e = (f & 1) * 4;
    const int dst = r * 512 + kg * 32 + ((c ^ ((r >> 1) & 3)) * 8) + e;
    f16x4 h;
    h.x = (f16)v.x; h.y = (f16)v.y; h.z = (f16)v.z; h.w = (f16)v.w;
    *(f16x4*)&out[dst] = h;
  }
}

// ---------------------------------------------------------------- fp16 MFMA GEMM, full-DMA
template <int OUT16>
__global__ __launch_bounds__(256, 4) void gemm_f16(const f16* __restrict__ A,
                                                   const f16* __restrict__ Bw,
                                                   const float* __restrict__ b1,
                                                   const float* __restrict__ b2,
                                                   float* __restrict__ C32,
                                                   f16* __restrict__ C16,
                                                   const int K, const int nY,
                                                   const int ncol1, const int ldc) {
  __shared__ __align__(16) f16 SMEM[16896];
  const int t = threadIdx.x;
  const int lane = t & 63;
  const int w = t >> 6;
  const int wr = w >> 1, wc = w & 1;

  const int id = blockIdx.x;
  const int xcd = id & 7;
  const int j = id >> 3;
  const int xpc = (int)(gridDim.x) / (nY * 8);
  const int xloc = j / nY;
  const int y = j - xloc * nY;
  const size_t bm = (size_t)(xcd * xpc + xloc) * 128;
  const int bn = y * 128;

  const int lr = lane & 15;
  const int ksl = lane >> 4;

  f32x4 acc[4][4] = {};

  auto stage = [&](int k0, int buf) {
    const int rsub = lane >> 2;
    const int csub = (lane & 3) * 8;
    const size_t ga = (bm + w * 32 + rsub) * (size_t)K + k0 + csub;
    const size_t gb = ((size_t)(bn + w * 32 + rsub)) * K + k0 + csub;
    f16* Ab = SMEM + buf * 4096;
    f16* Bb = SMEM + 8192 + buf * 4096;
    gl_lds16(A + ga,                   Ab + (w * 32) * 32);
    gl_lds16(A + ga + 16 * (size_t)K,  Ab + (w * 32 + 16) * 32);
    gl_lds16(Bw + gb,                  Bb + (w * 32) * 32);
    gl_lds16(Bw + gb + 16 * (size_t)K, Bb + (w * 32 + 16) * 32);
  };

  const int nsteps = K >> 5;
  stage(0, 0);
  for (int s = 0; s < nsteps; ++s) {
    const int buf = s & 1;
    __syncthreads();
    const f16* Ab = SMEM + buf * 4096;
    const f16* Bb = SMEM + 8192 + buf * 4096;
    f16x8 a[4], b[4];
#pragma unroll
    for (int i = 0; i < 4; ++i) {
      const int rA = wr * 64 + i * 16 + lr;
      a[i] = *(const f16x8*)&Ab[rA * 32 + ((ksl ^ ((rA >> 1) & 3)) * 8)];
      const int rB = wc * 64 + i * 16 + lr;
      b[i] = *(const f16x8*)&Bb[rB * 32 + ((ksl ^ ((rB >> 1) & 3)) * 8)];
    }
    if (s + 1 < nsteps) stage((s + 1) << 5, buf ^ 1);
#pragma unroll
    for (int mi = 0; mi < 4; ++mi)
#pragma unroll
      for (int ni = 0; ni < 4; ++ni)
        acc[mi][ni] = __builtin_amdgcn_mfma_f32_16x16x32_f16(a[mi], b[ni], acc[mi][ni], 0, 0, 0);
  }

  const int rg = (lane >> 4) << 2;
  if (OUT16) {
    __syncthreads();
#pragma unroll
    for (int ni = 0; ni < 4; ++ni) {
      const int cl = wc * 64 + ni * 16 + lr;
      const int cg = bn + cl;
      const float bs = (cg < ncol1) ? b1[cg] : b2[cg - ncol1];
#pragma unroll
      for (int mi = 0; mi < 4; ++mi)
#pragma unroll
        for (int j2 = 0; j2 < 4; ++j2)
          SMEM[(wr * 64 + mi * 16 + rg + j2) * 132 + cl] = (f16)(acc[mi][ni][j2] + bs);
    }
    __syncthreads();
#pragma unroll
    for (int i = 0; i < 8; ++i) {
      const int idx = i * 256 + t;
      const int rl = idx >> 4, ch = (idx & 15) * 8;
      *(f16x8*)&C16[(bm + rl) * (size_t)ldc + bn + ch] = *(const f16x8*)&SMEM[rl * 132 + ch];
    }
  } else {
#pragma unroll
    for (int ni = 0; ni < 4; ++ni) {
      const int col = bn + wc * 64 + ni * 16 + lr;
      const float bs = (col < ncol1) ? b1[col] : b2[col - ncol1];
#pragma unroll
      for (int mi = 0; mi < 4; ++mi) {
        float* Cp = C32 + (bm + wr * 64 + mi * 16 + rg) * (size_t)ldc + col;
#pragma unroll
        for (int j2 = 0; j2 < 4; ++j2)
          Cp[(size_t)j2 * ldc] = acc[mi][ni][j2] + bs;
      }
    }
  }
}

// ---------------------------------------------------------------- nonlinearity, wave-per-row, fp16 in-place (R14 proven)
__global__ __launch_bounds__(256) void nonlin16_kernel(f16* __restrict__ qkv,
                                                       const float* __restrict__ inv_s,
                                                       const float* __restrict__ ff) {
  const int t = threadIdx.x, lane = t & 63, w = t >> 6;
  const int row = blockIdx.x * 4 + w;
  f16* qr = qkv + (size_t)row * 1536 + lane * 8;
  f16* kr = qr + 512;
  f16x8 qh = *(const f16x8*)qr;
  f16x8 kh = *(const f16x8*)kr;
  float is[8], fv[8];
  *(float4*)&is[0] = *(const float4*)(inv_s + lane * 8);
  *(float4*)&is[4] = *(const float4*)(inv_s + lane * 8 + 4);
  *(float4*)&fv[0] = *(const float4*)(ff + lane * 8);
  *(float4*)&fv[4] = *(const float4*)(ff + lane * 8 + 4);

  float qv[8], kval[8], sq = 0.f, sk = 0.f;
#pragma unroll
  for (int i = 0; i < 8; ++i) {
    qv[i] = (fmaxf((float)qh[i], 0.f) + 1e-6f) * is[i];
    kval[i] = (fmaxf((float)kh[i], 0.f) + 1e-6f) * is[i];
    sq += qv[i] * qv[i];
    sk += kval[i] * kval[i];
  }
#pragma unroll
  for (int off = 1; off < 64; off <<= 1) {
    sq += __shfl_xor(sq, off);
    sk += __shfl_xor(sk, off);
  }
  const float qn = sqrtf(sq), kn = sqrtf(sk);

  float pq[8], pk[8], sq2 = 0.f, sk2 = 0.f;
#pragma unroll
  for (int i = 0; i < 8; ++i) {
    pq[i] = fast_pow(qv[i], fv[i]);
    pk[i] = fast_pow(kval[i], fv[i]);
    sq2 += pq[i] * pq[i];
    sk2 += pk[i] * pk[i];
  }
#pragma unroll
  for (int off = 1; off < 64; off <<= 1) {
    sq2 += __shfl_xor(sq2, off);
    sk2 += __shfl_xor(sk2, off);
  }
  const float qs = qn / sqrtf(sq2), ks = kn / sqrtf(sk2);
  f16x8 qo, ko;
#pragma unroll
  for (int i = 0; i < 8; ++i) {
    qo[i] = (f16)(pq[i] * qs);
    ko[i] = (f16)(pk[i] * ks);
  }
  *(f16x8*)qr = qo;
  *(f16x8*)kr = ko;
}

// ---------------------------------------------------------------- kv_mat via MFMA (+ fused ksum)
// Per block: one (bh, 512-token chunk). Each wave privately owns 128 tokens:
// stages 32-tok k/v tiles transposed to [ch][tok] (stride 40 -> 16B-aligned b128,
// ~2-way banks) in its OWN LDS region -> no block barriers in the K-loop
// (same-wave ds ordering via lgkmcnt). 16 MFMA/wave/step; ksum from a-frag sums.
__global__ __launch_bounds__(256) void kvmat_mfma_kernel(const f16* __restrict__ qkv,
                                                         float* __restrict__ kvm,
                                                         float* __restrict__ ksum) {
  __shared__ __align__(16) f16 ST[20480];   // 4 waves x (kT,vT)[64][40] = 40 KB
  const int bh = blockIdx.y;
  const int b = bh >> 3, h = bh & 7;
  const int chunk = blockIdx.x;
  const int t = threadIdx.x, lane = t & 63, w = t >> 6;
  f16* kT = ST + w * 5120;
  f16* vT = kT + 2560;
  const int tok = lane & 31, half = lane >> 5;
  const int lr = lane & 15, ksl = lane >> 4;
  f32x4 acc[4][4] = {};
  float kacc[4] = {0.f, 0.f, 0.f, 0.f};
  const int rowbase = b * N_TOK + chunk * 512 + w * 128;

  for (int s = 0; s < 4; ++s) {
    const size_t g = (size_t)(rowbase + s * 32 + tok) * 1536 + 512 + h * 64 + half * 32;
    f16x8 kr[4], vr[4];
#pragma unroll
    for (int j = 0; j < 4; ++j) {
      kr[j] = *(const f16x8*)&qkv[g + j * 8];
      vr[j] = *(const f16x8*)&qkv[g + 512 + j * 8];
    }
#pragma unroll
    for (int j = 0; j < 4; ++j)
#pragma unroll
      for (int e = 0; e < 8; ++e) {
        const int ch = half * 32 + j * 8 + e;
        kT[ch * 40 + tok] = kr[j][e];
        vT[ch * 40 + tok] = vr[j][e];
      }
    // reads below depend on the writes above; compiler orders via lgkmcnt
    f16x8 a[4], bv[4];
#pragma unroll
    for (int mi = 0; mi < 4; ++mi)
      a[mi] = *(const f16x8*)&kT[(mi * 16 + lr) * 40 + ksl * 8];
#pragma unroll
    for (int ni = 0; ni < 4; ++ni)
      bv[ni] = *(const f16x8*)&vT[(ni * 16 + lr) * 40 + ksl * 8];
#pragma unroll
    for (int mi = 0; mi < 4; ++mi) {
      float s8 = 0.f;
#pragma unroll
      for (int e = 0; e < 8; ++e) s8 += (float)a[mi][e];
      kacc[mi] += s8;
    }
#pragma unroll
    for (int mi = 0; mi < 4; ++mi)
#pragma unroll
      for (int ni = 0; ni < 4; ++ni)
        acc[mi][ni] = __builtin_amdgcn_mfma_f32_16x16x32_f16(a[mi], bv[ni], acc[mi][ni], 0, 0, 0);
  }

  // ksum: fold ksl slices (lanes 16/32 apart hold same channel), 1 atomic per ch per wave
#pragma unroll
  for (int mi = 0; mi < 4; ++mi) {
    kacc[mi] += __shfl_xor(kacc[mi], 16);
    kacc[mi] += __shfl_xor(kacc[mi], 32);
  }
  if (ksl == 0) {
#pragma unroll
    for (int mi = 0; mi < 4; ++mi)
      atomicAdd(&ksum[b * 512 + h * 64 + mi * 16 + lr], kacc[mi]);
  }

  // cross-wave C reduction: f32 [64][66] tile aliased over ST (all staging reads done)
  float* tile = (float*)ST;
  const int rg = (lane >> 4) << 2;
  __syncthreads();
  for (int ww = 0; ww < 4; ++ww) {
    if (w == ww) {
#pragma unroll
      for (int mi = 0; mi < 4; ++mi)
#pragma unroll
        for (int ni = 0; ni < 4; ++ni)
#pragma unroll
          for (int j2 = 0; j2 < 4; ++j2) {
            const int aidx = (mi * 16 + rg + j2) * 66 + ni * 16 + lr;
            tile[aidx] = (ww == 0) ? acc[mi][ni][j2] : tile[aidx] + acc[mi][ni][j2];
          }
    }
    __syncthreads();
  }
  const float scl = 1.0f / (float)N_TOK;
#pragma unroll
  for (int i = 0; i < 16; ++i) {
    const int idx = i * 256 + t;
    const int rr = idx >> 6, cc = idx & 63;
    atomicAdd(&kvm[(size_t)bh * 4096 + idx], tile[rr * 66 + cc] * scl);
  }
}

// ---------------------------------------------------------------- kvm fp32 -> transposed, chunk-swizzled fp16
__global__ void cvt_kvmT_kernel(const float* __restrict__ kvm, f16* __restrict__ kvmT16) {
  const int bh = blockIdx.x, t = threadIdx.x;
#pragma unroll
  for (int i = 0; i < 16; ++i) {
    const int e = i * 256 + t;            // 0..4095 = din*64 + d
    const int din = e >> 6, d = e & 63;
    const float v = kvm[(size_t)bh * 4096 + e];
    const int c = din >> 3, ce = din & 7;
    kvmT16[(size_t)bh * 4096 + d * 64 + ((c ^ (d & 7)) * 8) + ce] = (f16)v;
  }
}

// ---------------------------------------------------------------- MFMA attention (R14 proven) + setprio
__global__ __launch_bounds__(256, 4) void attn_mfma_kernel(const f16* __restrict__ qkv,
                                                           const f16* __restrict__ kvmT16,
                                                           const float* __restrict__ ksum,
                                                           f16* __restrict__ y16) {
  __shared__ __align__(16) f16 QS[128 * 64];   // [row][chunk ^ (row&7)]
  __shared__ __align__(16) f16 KM[64 * 64];    // [d][chunk ^ (d&7)] (pre-swizzled)
  __shared__ float kms[64];
  __shared__ float zl[128];
  const int bh = blockIdx.y;
  const int b = bh >> 3, h = bh & 7;
  const int tok0 = blockIdx.x * 128;
  const int t = threadIdx.x, lane = t & 63, w = t >> 6;

  // Q: 1024 chunks; coalesced loads, swizzled LDS stores
#pragma unroll
  for (int i = 0; i < 4; ++i) {
    const int idx = i * 256 + t;
    const int row = idx >> 3, ch = idx & 7;
    const f16x8 v = *(const f16x8*)&qkv[((size_t)(b * N_TOK) + tok0 + row) * 1536 + h * 64 + ch * 8];
    *(f16x8*)&QS[row * 64 + ((ch ^ (row & 7)) * 8)] = v;
  }
  // KM: verbatim vectorized copy
#pragma unroll
  for (int i = 0; i < 2; ++i) {
    const int idx = i * 256 + t;
    *(f16x8*)&KM[idx * 8] = *(const f16x8*)&kvmT16[(size_t)bh * 4096 + idx * 8];
  }
  if (t < 64) kms[t] = ksum[b * 512 + h * 64 + t];
  __syncthreads();

  // z per token: 2 threads/token, 32 din each
  {
    const int tok = t >> 1;
    const int ch0 = (t & 1) * 4;
    float p = 0.f;
#pragma unroll
    for (int c = 0; c < 4; ++c) {
      const int ch = ch0 + c;
      const f16x8 hv = *(const f16x8*)&QS[tok * 64 + ((ch ^ (tok & 7)) * 8)];
#pragma unroll
      for (int e = 0; e < 8; ++e) p += (float)hv[e] * kms[ch * 8 + e];
    }
    p += __shfl_xor(p, 1);
    if ((t & 1) == 0) zl[tok] = 1.0f / (p * (1.0f / (float)N_TOK) + 1e-6f);
  }
  __syncthreads();

  // fragments + MFMA
  const int lr = lane & 15, ksl = lane >> 4;
  f32x4 acc[2][4] = {};
  __builtin_amdgcn_s_setprio(1);
#pragma unroll
  for (int s = 0; s < 2; ++s) {
    f16x8 a[2], bfr[4];
#pragma unroll
    for (int mi = 0; mi < 2; ++mi) {
      const int row = w * 32 + mi * 16 + lr;
      a[mi] = *(const f16x8*)&QS[row * 64 + (((s * 4 + ksl) ^ (row & 7)) * 8)];
    }
#pragma unroll
    for (int ni = 0; ni < 4; ++ni) {
      const int dr = ni * 16 + lr;
      bfr[ni] = *(const f16x8*)&KM[dr * 64 + (((s * 4 + ksl) ^ (dr & 7)) * 8)];
    }
#pragma unroll
    for (int mi = 0; mi < 2; ++mi)
#pragma unroll
      for (int ni = 0; ni < 4; ++ni)
        acc[mi][ni] = __builtin_amdgcn_mfma_f32_16x16x32_f16(a[mi], bfr[ni], acc[mi][ni], 0, 0, 0);
  }
  __builtin_amdgcn_s_setprio(0);

  // epilogue: row = tokens, col = d (C/D layout col=lane&15, row=(lane>>4)*4+reg)
  const int rg = (lane >> 4) << 2;
#pragma unroll
  for (int mi = 0; mi < 2; ++mi)
#pragma unroll
    for (int ni = 0; ni < 4; ++ni)
#pragma unroll
      for (int j2 = 0; j2 < 4; ++j2) {
        const int row = w * 32 + mi * 16 + rg + j2;
        const int dcol = ni * 16 + lr;
        const float val = acc[mi][ni][j2] * zl[row];
        const int r = (int)(b * N_TOK) + tok0 + row;
        y16[(size_t)r * 512 + perm_col(h * 64 + dcol, r)] = (f16)val;
      }
}

// ---------------------------------------------------------------- depthwise 5x5 conv on v (fp16 in), RMW perm y16
__global__ __launch_bounds__(256, 4) void conv_kernel(const f16* __restrict__ qkv,
                                                      f16* __restrict__ y16,
                                                      const float* __restrict__ wconv,
                                                      const float* __restrict__ bconv) {
  __shared__ float vt[20 * 20 * 16];
  const int zidx = blockIdx.z;
  const int bh = zidx >> 2, cq = zidx & 3;
  const int b = bh >> 3, h = bh & 7;
  const int c0 = cq * 16;
  const int tx0 = blockIdx.x * 16, ty0 = blockIdx.y * 16;
  const int t = threadIdx.x;
  const size_t vcol = 1024 + h * 64 + c0;
#pragma unroll
  for (int i = 0; i < 7; ++i) {
    const int idx = i * 256 + t;
    if (idx < 1600) {
      const int pix = idx >> 2, c4 = (idx & 3) * 4;
      const int lx = pix % 20, ly = pix / 20;
      const int gx = tx0 + lx - 2, gy = ty0 + ly - 2;
      float4 val = make_float4(0.f, 0.f, 0.f, 0.f);
      if ((unsigned)gx < 128u && (unsigned)gy < 128u) {
        f16x4 hv = *(const f16x4*)&qkv[((size_t)(b * N_TOK) + gy * 128 + gx) * 1536 + vcol + c4];
        val = make_float4((float)hv.x, (float)hv.y, (float)hv.z, (float)hv.w);
      }
      *(float4*)&vt[pix * 16 + c4] = val;
    }
  }
  const int c = t & 15;
  const int dd = c0 + c;
  float w[25];
#pragma unroll
  for (int k = 0; k < 25; ++k) w[k] = wconv[dd * 25 + k];
  const float bb = bconv[dd];
  __syncthreads();
  const int slot = t >> 4;
  const int col = h * 64 + dd;
  for (int i = 0; i < 16; ++i) {
    const int pix = i * 16 + slot;
    const int px = pix & 15, py = pix >> 4;
    float acc = bb;
#pragma unroll
    for (int ky = 0; ky < 5; ++ky)
#pragma unroll
      for (int kx = 0; kx < 5; ++kx)
        acc = fmaf(w[ky * 5 + kx], vt[((py + ky) * 20 + (px + kx)) * 16 + c], acc);
    const int r = (int)(b * N_TOK) + (ty0 + py) * 128 + (tx0 + px);
    f16* p = &y16[(size_t)r * 512 + perm_col(col, r)];
    *p = (f16)((float)*p + acc);
  }
}

// ---------------------------------------------------------------- launch
extern "C" void kernel_launch(void* const* d_in, const int* in_sizes, int n_in,
                              void* d_out, int out_size, void* d_ws, size_t ws_size,
                              hipStream_t stream) {
  (void)n_in; (void)out_size;
  const float* x     = (const float*)d_in[0];
  const float* Wq    = (const float*)d_in[1];
  const float* bq    = (const float*)d_in[2];
  const float* Wkv   = (const float*)d_in[3];
  const float* bkv   = (const float*)d_in[4];
  const float* Wp    = (const float*)d_in[5];
  const float* bp    = (const float*)d_in[6];
  const float* ff    = (const float*)d_in[7];
  const float* scale = (const float*)d_in[8];
  const float* dwc_w = (const float*)d_in[9];
  const float* dwc_b = (const float*)d_in[10];

  const int B = in_sizes[0] / (N_TOK * CDIM);   // 4
  const int M = B * N_TOK;                      // 65536

  // ws layout: qkv16 [M][1536] fp16 | y16 [M][512] fp16 perm | ksum | kvm | scratch
  f16*   qkv16 = (f16*)d_ws;
  f16*   y16   = qkv16 + (size_t)M * 1536;
  float* ksum  = (float*)(y16 + (size_t)M * 512);
  float* kvm   = ksum + (size_t)B * 512;
  float* zscr  = kvm + (size_t)B * 8 * 4096;

  size_t need = ((size_t)M * 1536 + (size_t)B * 512 + (size_t)B * 8 * 4096 +
                 (size_t)B * 8 * N_TOK) * sizeof(float);   // known-good bound
  if (ws_size < need) {
    fprintf(stderr, "kernel_launch: ws too small (%zu < %zu)\n", ws_size, need);
    return;
  }

  // d_out head carve (dead until final GEMM): x16 (64 MB) + wqkv16 (1.5 MB)
  f16* x16    = (f16*)d_out;
  f16* wqkv16 = x16 + (size_t)M * 512;
  // z-scratch carve: wp16 (512 KB) + inv_s (2 KB) + kvmT16 (256 KB)
  f16* wp16    = (f16*)zscr;
  float* inv_s = zscr + 131072;
  f16* kvmT16  = (f16*)(inv_s + 512);

  const int nsmall = B * 512 + B * 8 * 4096;
  zero_kernel<<<(nsmall + 255) / 256, 256, 0, stream>>>(ksum, nsmall);
  sp_kernel<<<2, 256, 0, stream>>>(scale, inv_s);
  cvt_perm_kernel<<<4096, 256, 0, stream>>>(x, x16, M * 512 / 4);
  cvt_perm_kernel<<<256, 256, 0, stream>>>(Wq, wqkv16, 512 * 512 / 4);
  cvt_perm_kernel<<<512, 256, 0, stream>>>(Wkv, wqkv16 + 512 * 512, 1024 * 512 / 4);
  cvt_perm_kernel<<<256, 256, 0, stream>>>(Wp, wp16, 512 * 512 / 4);

  // fused q+kv projection -> fp16 qkv16 [M][1536] (raw, pre-nonlin)
  gemm_f16<1><<<(M / 128) * 12, 256, 0, stream>>>(x16, wqkv16, bq, bkv,
                                                  nullptr, qkv16, CDIM, 12, 512, 1536);

  nonlin16_kernel<<<M / 4, 256, 0, stream>>>(qkv16, inv_s, ff);
  kvmat_mfma_kernel<<<dim3(32, B * 8), 256, 0, stream>>>(qkv16, kvm, ksum);
  cvt_kvmT_kernel<<<B * 8, 256, 0, stream>>>(kvm, kvmT16);
  attn_mfma_kernel<<<dim3(N_TOK / 128, B * 8), 256, 0, stream>>>(qkv16, kvmT16, ksum, y16);
  conv_kernel<<<dim3(8, 8, B * 8 * 4), 256, 0, stream>>>(qkv16, y16, dwc_w, dwc_b);

  // output projection: fp32 into d_out (overwrites dead x16/wqkv16)
  gemm_f16<0><<<(M / 128) * 4, 256, 0, stream>>>(y16, wp16, bp, bp,
                                                 (float*)d_out, nullptr, CDIM, 4, 512, 512);
}